// Round 1
// baseline (341.211 us; speedup 1.0000x reference)
//
#include <hip/hip_runtime.h>

typedef __bf16 bf16x8 __attribute__((ext_vector_type(8)));
typedef float f32x4 __attribute__((ext_vector_type(4)));
typedef unsigned short u16x4 __attribute__((ext_vector_type(4)));

#define L2E 1.44269504088896340736f

__device__ __forceinline__ f32x4 mfma16(bf16x8 a, bf16x8 b, f32x4 c) {
  return __builtin_amdgcn_mfma_f32_16x16x32_bf16(a, b, c, 0, 0, 0);
}

// global -> LDS direct copy, 16B per lane. LDS dest must be wave-uniform;
// lane l lands at dest + l*16 bytes.
__device__ __forceinline__ void async16(const __bf16* g, __bf16* l) {
  __builtin_amdgcn_global_load_lds(
      (const __attribute__((address_space(1))) void*)g,
      (__attribute__((address_space(3))) void*)l, 16, 0, 0);
}

// ---------------- fp32 -> bf16 conversion (vectorized) ----------------
__global__ __launch_bounds__(256) void cvt_bf16(const float* __restrict__ s,
                                                __bf16* __restrict__ d) {
  long i = (long)(blockIdx.x * 256 + threadIdx.x) * 4;
  f32x4 v = *(const f32x4*)(s + i);
  u16x4 o;
#pragma unroll
  for (int j = 0; j < 4; j++) o[j] = __builtin_bit_cast(unsigned short, (__bf16)v[j]);
  *(u16x4*)((unsigned short*)d + i) = o;
}

// ---------------- bf16 GEMM: C[M,N] = A[M,K] @ Bt[N,K]^T ----------------
// 128x128 tile, BK=32, 4 waves, 16x16x32 MFMA, global_load_lds staging.
// LDS layout swizzled: tile[row][c] stored at LDS[row*32 + (c ^ 8*(row&3))].
template <int OUTF32>
__global__ __launch_bounds__(256, 2) void gemm_bt(
    const __bf16* __restrict__ A, const __bf16* __restrict__ Bt,
    void* __restrict__ Cout, const float* __restrict__ bias,
    int M, int N, int K, float scale) {
  (void)M;
  __shared__ __align__(16) __bf16 As[4096];
  __shared__ __align__(16) __bf16 Bs[4096];
  const int tid = threadIdx.x;
  const int wid = tid >> 6, lane = tid & 63;
  const int lrow = lane & 15, lkhi = lane >> 4;
  const int row0 = blockIdx.x * 128, col0 = blockIdx.y * 128;
  const int wr = (wid >> 1) * 64, wc = (wid & 1) * 64;

  // staging: thread tid covers LDS elements tid*8..+7 (issue 0) / +2048 (issue 1)
  const int trow = tid >> 2;                       // tile row within issue
  const int scol = 8 * ((tid & 3) ^ (trow & 3));   // pre-swizzled source col
  const __bf16* pA0 = A + (size_t)(row0 + trow) * K + scol;
  const __bf16* pA1 = pA0 + (size_t)64 * K;
  const __bf16* pB0 = Bt + (size_t)(col0 + trow) * K + scol;
  const __bf16* pB1 = pB0 + (size_t)64 * K;
  __bf16* lA0 = As + wid * 512;
  __bf16* lA1 = As + 2048 + wid * 512;
  __bf16* lB0 = Bs + wid * 512;
  __bf16* lB1 = Bs + 2048 + wid * 512;

  int aoff[4], boff[4];
#pragma unroll
  for (int i = 0; i < 4; i++) {
    int rr = wr + i * 16 + lrow;
    aoff[i] = rr * 32 + 8 * (lkhi ^ (rr & 3));
    rr = wc + i * 16 + lrow;
    boff[i] = rr * 32 + 8 * (lkhi ^ (rr & 3));
  }

  f32x4 acc[4][4] = {};
  for (int k0 = 0; k0 < K; k0 += 32) {
    __syncthreads();  // prev compute done before overwriting LDS
    async16(pA0, lA0);
    async16(pA1, lA1);
    async16(pB0, lB0);
    async16(pB1, lB1);
    pA0 += 32; pA1 += 32; pB0 += 32; pB1 += 32;
    __syncthreads();  // staging visible (compiler drains vmcnt before barrier)
    bf16x8 af[4], bv[4];
#pragma unroll
    for (int mi = 0; mi < 4; mi++) af[mi] = *(const bf16x8*)(As + aoff[mi]);
#pragma unroll
    for (int ni = 0; ni < 4; ni++) bv[ni] = *(const bf16x8*)(Bs + boff[ni]);
#pragma unroll
    for (int mi = 0; mi < 4; mi++)
#pragma unroll
      for (int ni = 0; ni < 4; ni++)
        acc[mi][ni] = mfma16(af[mi], bv[ni], acc[mi][ni]);
  }

  const int orow = row0 + wr + lkhi * 4;
  const int ocol = col0 + wc + lrow;
#pragma unroll
  for (int mi = 0; mi < 4; mi++)
#pragma unroll
    for (int ni = 0; ni < 4; ni++)
#pragma unroll
      for (int r = 0; r < 4; r++) {
        size_t idx = (size_t)(orow + mi * 16 + r) * N + (ocol + ni * 16);
        float v = acc[mi][ni][r] * scale;
        if (OUTF32)
          ((float*)Cout)[idx] = v + bias[ocol + ni * 16];
        else
          ((__bf16*)Cout)[idx] = (__bf16)v;
      }
}

// ---------------- causal flash attention ----------------
// Qf,Kf: [B*T, H*DH] bf16 (Q pre-scaled by 1/sqrt(DH)); Vt: [H*DH, B*T] bf16.
// Grid: 512 = B(2) * H(16) * (T/128=16). Block: 256 thr = 4 waves x 32 q-rows.
__global__ __launch_bounds__(256, 2) void mla_attn(
    const __bf16* __restrict__ Qf, const __bf16* __restrict__ Kf,
    const __bf16* __restrict__ Vt, __bf16* __restrict__ ctx) {
  __shared__ __align__(16) __bf16 Ks[64 * 128];   // [key][dh], swizzled &7
  __shared__ __align__(16) __bf16 Vs[128 * 64];   // [dh][key], swizzled &7
  __shared__ __align__(16) __bf16 Ps[4][32 * 64]; // per-wave P, swizzled &7

  const int bid = blockIdx.x;
  const int qb = bid & 15, h = (bid >> 4) & 15, b = bid >> 8;
  const int tid = threadIdx.x, wid = tid >> 6, lane = tid & 63;
  const int lrow = lane & 15, lkhi = lane >> 4;
  const int q0 = qb * 128;

  // Q fragments in registers (A-operand layout), read once.
  bf16x8 qa[2][4];
#pragma unroll
  for (int mi = 0; mi < 2; mi++)
#pragma unroll
    for (int kk = 0; kk < 4; kk++)
      qa[mi][kk] = *(const bf16x8*)(Qf +
          (size_t)(b * 2048 + q0 + wid * 32 + mi * 16 + lrow) * 2048 +
          h * 128 + kk * 32 + lkhi * 8);

  f32x4 o_acc[2][8] = {};
  float mrow[2][4], lsum[2][4];
#pragma unroll
  for (int mi = 0; mi < 2; mi++)
#pragma unroll
    for (int r = 0; r < 4; r++) { mrow[mi][r] = -1e30f; lsum[mi][r] = 0.f; }

  __bf16* ps = &Ps[wid][0];
  const int nkv = (q0 + 128) >> 6;

  for (int kb = 0; kb < nkv; kb++) {
    const int k0 = kb * 64;
    __syncthreads();
    // stage K tile 64x128 (row stride 256B, swizzle (row&7)<<4 via source perm)
#pragma unroll
    for (int i = 0; i < 4; i++) {
      int oe = i * 2048 + tid * 8;
      int row = oe >> 7;
      int cs = (oe & 127) ^ (8 * (row & 7));
      async16(Kf + (size_t)(b * 2048 + k0 + row) * 2048 + h * 128 + cs,
              Ks + i * 2048 + wid * 512);
    }
    // stage V^T tile 128x64 (row stride 128B)
#pragma unroll
    for (int i = 0; i < 4; i++) {
      int oe = i * 2048 + tid * 8;
      int row = oe >> 6;
      int cs = (oe & 63) ^ (8 * (row & 7));
      async16(Vt + (size_t)(h * 128 + row) * 4096 + b * 2048 + k0 + cs,
              Vs + i * 2048 + wid * 512);
    }
    __syncthreads();

    // S = Q K^T (contraction over dh)
    f32x4 s_acc[2][4] = {};
#pragma unroll
    for (int kk = 0; kk < 4; kk++) {
      bf16x8 kf[4];
#pragma unroll
      for (int ni = 0; ni < 4; ni++) {
        int row = ni * 16 + lrow;
        kf[ni] = *(const bf16x8*)(Ks + row * 128 +
                                  ((kk * 32 + lkhi * 8) ^ (8 * (row & 7))));
      }
#pragma unroll
      for (int mi = 0; mi < 2; mi++)
#pragma unroll
        for (int ni = 0; ni < 4; ni++)
          s_acc[mi][ni] = mfma16(qa[mi][kk], kf[ni], s_acc[mi][ni]);
    }

    // causal mask (only the two diagonal-adjacent KV blocks need it)
    if (k0 + 64 > q0) {
#pragma unroll
      for (int mi = 0; mi < 2; mi++)
#pragma unroll
        for (int ni = 0; ni < 4; ni++)
#pragma unroll
          for (int r = 0; r < 4; r++) {
            int q = q0 + wid * 32 + mi * 16 + lkhi * 4 + r;
            int kx = k0 + ni * 16 + lrow;
            if (kx > q) s_acc[mi][ni][r] = -1e30f;
          }
    }

    // online softmax: rows live in lanes sharing lkhi; reduce over lrow lanes
#pragma unroll
    for (int mi = 0; mi < 2; mi++)
#pragma unroll
      for (int r = 0; r < 4; r++) {
        float bm = fmaxf(fmaxf(s_acc[mi][0][r], s_acc[mi][1][r]),
                         fmaxf(s_acc[mi][2][r], s_acc[mi][3][r]));
        bm = fmaxf(bm, __shfl_xor(bm, 1));
        bm = fmaxf(bm, __shfl_xor(bm, 2));
        bm = fmaxf(bm, __shfl_xor(bm, 4));
        bm = fmaxf(bm, __shfl_xor(bm, 8));
        float mn = fmaxf(mrow[mi][r], bm);
        float sf = __builtin_amdgcn_exp2f((mrow[mi][r] - mn) * L2E);
        mrow[mi][r] = mn;
        lsum[mi][r] *= sf;
#pragma unroll
        for (int n2 = 0; n2 < 8; n2++) o_acc[mi][n2][r] *= sf;
        float psum = 0.f;
        int prow = mi * 16 + lkhi * 4 + r;
#pragma unroll
        for (int ni = 0; ni < 4; ni++) {
          float p = __builtin_amdgcn_exp2f((s_acc[mi][ni][r] - mn) * L2E);
          psum += p;
          int col = ni * 16 + lrow;
          ps[prow * 64 + (col ^ (8 * (prow & 7)))] = (__bf16)p;
        }
        psum += __shfl_xor(psum, 1);
        psum += __shfl_xor(psum, 2);
        psum += __shfl_xor(psum, 4);
        psum += __shfl_xor(psum, 8);
        lsum[mi][r] += psum;
      }

    // O += P V (contraction over keys; P from per-wave LDS, V^T gives
    // contiguous-key B-operand reads)
#pragma unroll
    for (int kk = 0; kk < 2; kk++) {
      bf16x8 pa[2];
#pragma unroll
      for (int mi = 0; mi < 2; mi++) {
        int row = mi * 16 + lrow;
        pa[mi] = *(const bf16x8*)(ps + row * 64 +
                                  ((kk * 32 + lkhi * 8) ^ (8 * (row & 7))));
      }
#pragma unroll
      for (int n2 = 0; n2 < 8; n2++) {
        int vrow = n2 * 16 + lrow;
        bf16x8 vf = *(const bf16x8*)(Vs + vrow * 64 +
                                     ((kk * 32 + lkhi * 8) ^ (8 * (vrow & 7))));
#pragma unroll
        for (int mi = 0; mi < 2; mi++)
          o_acc[mi][n2] = mfma16(pa[mi], vf, o_acc[mi][n2]);
      }
    }
  }

  // normalize and write ctx [B*T, H*DH] bf16
#pragma unroll
  for (int mi = 0; mi < 2; mi++)
#pragma unroll
    for (int r = 0; r < 4; r++) {
      float inv = 1.f / lsum[mi][r];
      size_t rowi = (size_t)(b * 2048 + q0 + wid * 32 + mi * 16 + lkhi * 4 + r) * 2048 +
                    h * 128;
#pragma unroll
      for (int n2 = 0; n2 < 8; n2++)
        ctx[rowi + n2 * 16 + lrow] = (__bf16)(o_acc[mi][n2][r] * inv);
    }
}

// ---------------- launch ----------------
extern "C" void kernel_launch(void* const* d_in, const int* in_sizes, int n_in,
                              void* d_out, int out_size, void* d_ws, size_t ws_size,
                              hipStream_t stream) {
  (void)in_sizes; (void)n_in; (void)out_size; (void)ws_size;
  const float* x    = (const float*)d_in[0];
  const float* wqd  = (const float*)d_in[1];
  const float* wkvd = (const float*)d_in[2];
  const float* wqup = (const float*)d_in[3];
  const float* wkup = (const float*)d_in[4];
  const float* wvup = (const float*)d_in[5];
  const float* wo   = (const float*)d_in[6];
  const float* bo   = (const float*)d_in[7];

  char* ws = (char*)d_ws;
  const size_t MB = 1024 * 1024;
  __bf16* x_bf    = (__bf16*)(ws + 0);        // 16MB; reused as ctx
  __bf16* q_full  = (__bf16*)(ws + 16 * MB);  // 16MB
  __bf16* k_full  = (__bf16*)(ws + 32 * MB);  // 16MB
  __bf16* vt      = (__bf16*)(ws + 48 * MB);  // 16MB
  __bf16* q_lat   = (__bf16*)(ws + 64 * MB);  // 8MB; reused as wo_bf
  __bf16* c_kv    = (__bf16*)(ws + 72 * MB);  // 4MB
  __bf16* wqd_bf  = (__bf16*)(ws + 76 * MB);  // 4MB
  __bf16* wkvd_bf = (__bf16*)(ws + 80 * MB);  // 2MB
  __bf16* wqup_bf = (__bf16*)(ws + 82 * MB);  // 4MB
  __bf16* wkup_bf = (__bf16*)(ws + 86 * MB);  // 2MB
  __bf16* wvup_bf = (__bf16*)(ws + 88 * MB);  // 2MB  -> total 90MB
  __bf16* ctx   = x_bf;   // x_bf dead after G2
  __bf16* wo_bf = q_lat;  // q_lat dead after G3

  auto cvt = [&](const float* s, __bf16* d, int n) {
    cvt_bf16<<<n / 1024, 256, 0, stream>>>(s, d);
  };
  cvt(x, x_bf, 4096 * 2048);
  cvt(wqd, wqd_bf, 1024 * 2048);
  cvt(wkvd, wkvd_bf, 512 * 2048);
  cvt(wqup, wqup_bf, 2048 * 1024);
  cvt(wkup, wkup_bf, 2048 * 512);
  cvt(wvup, wvup_bf, 2048 * 512);

  dim3 blk(256);
  // Q_lat = x @ Wq_down^T
  gemm_bt<0><<<dim3(32, 8), blk, 0, stream>>>(x_bf, wqd_bf, q_lat, nullptr,
                                              4096, 1024, 2048, 1.0f);
  // C_kv = x @ Wkv_down^T
  gemm_bt<0><<<dim3(32, 4), blk, 0, stream>>>(x_bf, wkvd_bf, c_kv, nullptr,
                                              4096, 512, 2048, 1.0f);
  // Q = Q_lat @ Wq_up^T, pre-scaled by 1/sqrt(128)
  gemm_bt<0><<<dim3(32, 16), blk, 0, stream>>>(q_lat, wqup_bf, q_full, nullptr,
                                               4096, 2048, 1024,
                                               0.08838834764831845f);
  cvt(wo, wo_bf, 2048 * 2048);  // after G3: q_lat region is free
  // K = C_kv @ Wk_up^T
  gemm_bt<0><<<dim3(32, 16), blk, 0, stream>>>(c_kv, wkup_bf, k_full, nullptr,
                                               4096, 2048, 512, 1.0f);
  // V^T = Wv_up @ C_kv^T  (same kernel, operand roles swapped)
  gemm_bt<0><<<dim3(16, 32), blk, 0, stream>>>(wvup_bf, c_kv, vt, nullptr,
                                               2048, 4096, 512, 1.0f);
  // ctx = causal_attention(Q, K, V)
  mla_attn<<<512, blk, 0, stream>>>(q_full, k_full, vt, ctx);
  // out = ctx @ Wo^T + bo  (fp32)
  gemm_bt<1><<<dim3(32, 16), blk, 0, stream>>>(ctx, wo_bf, (float*)d_out, bo,
                                               4096, 2048, 2048, 1.0f);
}

// Round 2
// 333.425 us; speedup vs baseline: 1.0234x; 1.0234x over previous
//
#include <hip/hip_runtime.h>

typedef __bf16 bf16x8 __attribute__((ext_vector_type(8)));
typedef float f32x4 __attribute__((ext_vector_type(4)));
typedef unsigned short u16x4 __attribute__((ext_vector_type(4)));

#define L2E 1.44269504088896340736f

__device__ __forceinline__ f32x4 mfma16(bf16x8 a, bf16x8 b, f32x4 c) {
  return __builtin_amdgcn_mfma_f32_16x16x32_bf16(a, b, c, 0, 0, 0);
}

// global -> LDS direct copy, 16B per lane. LDS dest must be wave-uniform;
// lane l lands at dest + l*16 bytes.
__device__ __forceinline__ void async16(const __bf16* g, __bf16* l) {
  __builtin_amdgcn_global_load_lds(
      (const __attribute__((address_space(1))) void*)g,
      (__attribute__((address_space(3))) void*)l, 16, 0, 0);
}

// ---------------- fp32 -> bf16 conversion (vectorized) ----------------
__global__ __launch_bounds__(256) void cvt_bf16(const float* __restrict__ s,
                                                __bf16* __restrict__ d) {
  long i = (long)(blockIdx.x * 256 + threadIdx.x) * 4;
  f32x4 v = *(const f32x4*)(s + i);
  u16x4 o;
#pragma unroll
  for (int j = 0; j < 4; j++) o[j] = __builtin_bit_cast(unsigned short, (__bf16)v[j]);
  *(u16x4*)((unsigned short*)d + i) = o;
}

// ---------------- bf16 GEMM: C[M,N] = A[M,K] @ Bt[N,K]^T ----------------
// 128x128 tile, BK=32, 4 waves, 16x16x32 MFMA, global_load_lds staging.
// Strided views supported (lda/ldb/ldc) so fused buffers can be sliced.
// LDS layout swizzled: tile[row][c] stored at LDS[row*32 + (c ^ 8*(row&3))].
template <int OUTF32>
__global__ __launch_bounds__(256, 2) void gemm_bt(
    const __bf16* __restrict__ A, const __bf16* __restrict__ Bt,
    void* __restrict__ Cout, const float* __restrict__ bias,
    int lda, int ldb, int ldc, int N, int K, float scale) {
  __shared__ __align__(16) __bf16 As[4096];
  __shared__ __align__(16) __bf16 Bs[4096];
  const int tid = threadIdx.x;
  const int wid = tid >> 6, lane = tid & 63;
  const int lrow = lane & 15, lkhi = lane >> 4;
  const int row0 = blockIdx.x * 128, col0 = blockIdx.y * 128;
  const int wr = (wid >> 1) * 64, wc = (wid & 1) * 64;

  // staging: thread tid covers LDS elements tid*8..+7 (issue 0) / +2048 (issue 1)
  const int trow = tid >> 2;                       // tile row within issue
  const int scol = 8 * ((tid & 3) ^ (trow & 3));   // pre-swizzled source col
  const __bf16* pA0 = A + (size_t)(row0 + trow) * lda + scol;
  const __bf16* pA1 = pA0 + (size_t)64 * lda;
  const __bf16* pB0 = Bt + (size_t)(col0 + trow) * ldb + scol;
  const __bf16* pB1 = pB0 + (size_t)64 * ldb;
  __bf16* lA0 = As + wid * 512;
  __bf16* lA1 = As + 2048 + wid * 512;
  __bf16* lB0 = Bs + wid * 512;
  __bf16* lB1 = Bs + 2048 + wid * 512;

  int aoff[4], boff[4];
#pragma unroll
  for (int i = 0; i < 4; i++) {
    int rr = wr + i * 16 + lrow;
    aoff[i] = rr * 32 + 8 * (lkhi ^ (rr & 3));
    rr = wc + i * 16 + lrow;
    boff[i] = rr * 32 + 8 * (lkhi ^ (rr & 3));
  }

  f32x4 acc[4][4] = {};
  for (int k0 = 0; k0 < K; k0 += 32) {
    __syncthreads();  // prev compute done before overwriting LDS
    async16(pA0, lA0);
    async16(pA1, lA1);
    async16(pB0, lB0);
    async16(pB1, lB1);
    pA0 += 32; pA1 += 32; pB0 += 32; pB1 += 32;
    __syncthreads();  // staging visible (compiler drains vmcnt before barrier)
    bf16x8 af[4], bv[4];
#pragma unroll
    for (int mi = 0; mi < 4; mi++) af[mi] = *(const bf16x8*)(As + aoff[mi]);
#pragma unroll
    for (int ni = 0; ni < 4; ni++) bv[ni] = *(const bf16x8*)(Bs + boff[ni]);
#pragma unroll
    for (int mi = 0; mi < 4; mi++)
#pragma unroll
      for (int ni = 0; ni < 4; ni++)
        acc[mi][ni] = mfma16(af[mi], bv[ni], acc[mi][ni]);
  }

  const int orow = row0 + wr + lkhi * 4;
  const int ocol = col0 + wc + lrow;
#pragma unroll
  for (int mi = 0; mi < 4; mi++)
#pragma unroll
    for (int ni = 0; ni < 4; ni++)
#pragma unroll
      for (int r = 0; r < 4; r++) {
        size_t idx = (size_t)(orow + mi * 16 + r) * ldc + (ocol + ni * 16);
        float v = acc[mi][ni][r] * scale;
        if (OUTF32)
          ((float*)Cout)[idx] = v + bias[ocol + ni * 16];
        else
          ((__bf16*)Cout)[idx] = (__bf16)v;
      }
}

// ---------------- causal flash attention (balanced pairs) ----------------
// Qf,Kf: [B*T, H*DH] bf16 (Q pre-scaled by 1/sqrt(DH)); Vt: [H*DH, B*T] bf16.
// Grid: 512 = B(2) * H(16) * 16 pair-index j. Block handles the 64-row
// q-tile pair {j, 31-j} sequentially -> uniform 33 KV-tiles per block.
// Block: 256 thr = 4 waves x 16 q-rows.
__global__ __launch_bounds__(256, 4) void mla_attn(
    const __bf16* __restrict__ Qf, const __bf16* __restrict__ Kf,
    const __bf16* __restrict__ Vt, __bf16* __restrict__ ctx) {
  __shared__ __align__(16) __bf16 Ks[64 * 128];   // [key][dh], swizzled &7
  __shared__ __align__(16) __bf16 Vs[128 * 64];   // [dh][key], swizzled &7
  __shared__ __align__(16) __bf16 Ps[4][16 * 64]; // per-wave P, swizzled &7

  // XCD-aware swizzle: 512 blocks, 8 XCDs -> give each XCD a contiguous
  // run of 64 original indices (2 (b,h) groups with all their j's).
  const int bid = (int)((blockIdx.x & 7) * 64 + (blockIdx.x >> 3));
  const int j = bid & 15, h = (bid >> 4) & 15, b = bid >> 8;
  const int tid = threadIdx.x, wid = tid >> 6, lane = tid & 63;
  const int lrow = lane & 15, lkhi = lane >> 4;
  __bf16* ps = &Ps[wid][0];

#pragma unroll
  for (int seg = 0; seg < 2; seg++) {
    const int qt = seg ? (31 - j) : j;  // 64-row q-tile index
    const int q0 = qt * 64;
    const int nkv = qt + 1;             // KV tiles of 64 keys

    // Q fragments in registers (A-operand layout), read once per segment.
    bf16x8 qa[4];
#pragma unroll
    for (int kk = 0; kk < 4; kk++)
      qa[kk] = *(const bf16x8*)(Qf +
          (size_t)(b * 2048 + q0 + wid * 16 + lrow) * 2048 +
          h * 128 + kk * 32 + lkhi * 8);

    f32x4 o_acc[8] = {};
    float mrow[4], lsum[4];
#pragma unroll
    for (int r = 0; r < 4; r++) { mrow[r] = -1e30f; lsum[r] = 0.f; }

    for (int kb = 0; kb < nkv; kb++) {
      const int k0 = kb * 64;
      __syncthreads();
      // stage K tile 64x128 (row stride 256B, swizzle (row&7)<<4 via src perm)
#pragma unroll
      for (int i = 0; i < 4; i++) {
        int oe = i * 2048 + tid * 8;
        int row = oe >> 7;
        int cs = (oe & 127) ^ (8 * (row & 7));
        async16(Kf + (size_t)(b * 2048 + k0 + row) * 2048 + h * 128 + cs,
                Ks + i * 2048 + wid * 512);
      }
      // stage V^T tile 128x64 (row stride 128B)
#pragma unroll
      for (int i = 0; i < 4; i++) {
        int oe = i * 2048 + tid * 8;
        int row = oe >> 6;
        int cs = (oe & 63) ^ (8 * (row & 7));
        async16(Vt + (size_t)(h * 128 + row) * 4096 + b * 2048 + k0 + cs,
                Vs + i * 2048 + wid * 512);
      }
      __syncthreads();

      // S = Q K^T (contraction over dh)
      f32x4 s_acc[4] = {};
#pragma unroll
      for (int kk = 0; kk < 4; kk++) {
        bf16x8 kf[4];
#pragma unroll
        for (int ni = 0; ni < 4; ni++) {
          int row = ni * 16 + lrow;
          kf[ni] = *(const bf16x8*)(Ks + row * 128 +
                                    ((kk * 32 + lkhi * 8) ^ (8 * (row & 7))));
        }
#pragma unroll
        for (int ni = 0; ni < 4; ni++)
          s_acc[ni] = mfma16(qa[kk], kf[ni], s_acc[ni]);
      }

      // causal mask: only the final KV tile of a segment crosses the diagonal
      if (k0 + 64 > q0) {
#pragma unroll
        for (int ni = 0; ni < 4; ni++)
#pragma unroll
          for (int r = 0; r < 4; r++) {
            int q = q0 + wid * 16 + lkhi * 4 + r;
            int kx = k0 + ni * 16 + lrow;
            if (kx > q) s_acc[ni][r] = -1e30f;
          }
      }

      // online softmax: rows live in lanes sharing lkhi; reduce over lrow lanes
#pragma unroll
      for (int r = 0; r < 4; r++) {
        float bm = fmaxf(fmaxf(s_acc[0][r], s_acc[1][r]),
                         fmaxf(s_acc[2][r], s_acc[3][r]));
        bm = fmaxf(bm, __shfl_xor(bm, 1));
        bm = fmaxf(bm, __shfl_xor(bm, 2));
        bm = fmaxf(bm, __shfl_xor(bm, 4));
        bm = fmaxf(bm, __shfl_xor(bm, 8));
        float mn = fmaxf(mrow[r], bm);
        float sf = __builtin_amdgcn_exp2f((mrow[r] - mn) * L2E);
        mrow[r] = mn;
        lsum[r] *= sf;
#pragma unroll
        for (int n2 = 0; n2 < 8; n2++) o_acc[n2][r] *= sf;
        float psum = 0.f;
        int prow = lkhi * 4 + r;
#pragma unroll
        for (int ni = 0; ni < 4; ni++) {
          float p = __builtin_amdgcn_exp2f((s_acc[ni][r] - mn) * L2E);
          psum += p;
          int col = ni * 16 + lrow;
          ps[prow * 64 + (col ^ (8 * (prow & 7)))] = (__bf16)p;
        }
        psum += __shfl_xor(psum, 1);
        psum += __shfl_xor(psum, 2);
        psum += __shfl_xor(psum, 4);
        psum += __shfl_xor(psum, 8);
        lsum[r] += psum;
      }

      // O += P V (contraction over keys; P from per-wave LDS, V^T gives
      // contiguous-key B-operand reads)
#pragma unroll
      for (int kk = 0; kk < 2; kk++) {
        int row = lrow;
        bf16x8 pa = *(const bf16x8*)(ps + row * 64 +
                                     ((kk * 32 + lkhi * 8) ^ (8 * (row & 7))));
#pragma unroll
        for (int n2 = 0; n2 < 8; n2++) {
          int vrow = n2 * 16 + lrow;
          bf16x8 vf = *(const bf16x8*)(Vs + vrow * 64 +
                                       ((kk * 32 + lkhi * 8) ^ (8 * (vrow & 7))));
          o_acc[n2] = mfma16(pa, vf, o_acc[n2]);
        }
      }
    }

    // normalize and write ctx [B*T, H*DH] bf16
#pragma unroll
    for (int r = 0; r < 4; r++) {
      float inv = 1.f / lsum[r];
      size_t rowi = (size_t)(b * 2048 + q0 + wid * 16 + lkhi * 4 + r) * 2048 +
                    h * 128;
#pragma unroll
      for (int n2 = 0; n2 < 8; n2++)
        ctx[rowi + n2 * 16 + lrow] = (__bf16)(o_acc[n2][r] * inv);
    }
    __syncthreads();  // all PV reads done before next segment restages LDS
  }
}

// ---------------- launch ----------------
extern "C" void kernel_launch(void* const* d_in, const int* in_sizes, int n_in,
                              void* d_out, int out_size, void* d_ws, size_t ws_size,
                              hipStream_t stream) {
  (void)in_sizes; (void)n_in; (void)out_size; (void)ws_size;
  const float* x    = (const float*)d_in[0];
  const float* wqd  = (const float*)d_in[1];
  const float* wkvd = (const float*)d_in[2];
  const float* wqup = (const float*)d_in[3];
  const float* wkup = (const float*)d_in[4];
  const float* wvup = (const float*)d_in[5];
  const float* wo   = (const float*)d_in[6];
  const float* bo   = (const float*)d_in[7];

  char* ws = (char*)d_ws;
  const size_t MB = 1024 * 1024;
  __bf16* x_bf     = (__bf16*)(ws + 0);        // 16MB; reused as ctx
  __bf16* q_full   = (__bf16*)(ws + 16 * MB);  // 16MB
  __bf16* k_full   = (__bf16*)(ws + 32 * MB);  // 16MB
  __bf16* vt       = (__bf16*)(ws + 48 * MB);  // 16MB
  __bf16* qkv_lat  = (__bf16*)(ws + 64 * MB);  // 12MB [4096,1536]; reused wo_bf
  __bf16* wqkvd_bf = (__bf16*)(ws + 76 * MB);  // 6MB  [1536,2048] fused
  __bf16* wqup_bf  = (__bf16*)(ws + 82 * MB);  // 4MB
  __bf16* wkup_bf  = (__bf16*)(ws + 86 * MB);  // 2MB
  __bf16* wvup_bf  = (__bf16*)(ws + 88 * MB);  // 2MB -> total 90MB
  __bf16* ctx   = x_bf;      // x_bf dead after fused down-proj
  __bf16* wo_bf = qkv_lat;   // qkv_lat dead after V^T GEMM

  auto cvt = [&](const float* s, __bf16* d, int n) {
    cvt_bf16<<<n / 1024, 256, 0, stream>>>(s, d);
  };
  cvt(x, x_bf, 4096 * 2048);
  cvt(wqd, wqkvd_bf, 1024 * 2048);                  // rows 0..1023
  cvt(wkvd, wqkvd_bf + 1024 * 2048, 512 * 2048);    // rows 1024..1535
  cvt(wqup, wqup_bf, 2048 * 1024);
  cvt(wkup, wkup_bf, 2048 * 512);
  cvt(wvup, wvup_bf, 2048 * 512);

  dim3 blk(256);
  // [Q_lat | C_kv] = x @ [Wq_down; Wkv_down]^T   (fused, N=1536)
  gemm_bt<0><<<dim3(32, 12), blk, 0, stream>>>(x_bf, wqkvd_bf, qkv_lat, nullptr,
                                               2048, 2048, 1536, 1536, 2048, 1.0f);
  // Q = Q_lat @ Wq_up^T, pre-scaled by 1/sqrt(128)
  gemm_bt<0><<<dim3(32, 16), blk, 0, stream>>>(qkv_lat, wqup_bf, q_full, nullptr,
                                               1536, 1024, 2048, 2048, 1024,
                                               0.08838834764831845f);
  // K = C_kv @ Wk_up^T
  gemm_bt<0><<<dim3(32, 16), blk, 0, stream>>>(qkv_lat + 1024, wkup_bf, k_full,
                                               nullptr, 1536, 512, 2048, 2048,
                                               512, 1.0f);
  // V^T = Wv_up @ C_kv^T  (same kernel, operand roles swapped)
  gemm_bt<0><<<dim3(16, 32), blk, 0, stream>>>(wvup_bf, qkv_lat + 1024, vt,
                                               nullptr, 512, 1536, 4096, 4096,
                                               512, 1.0f);
  cvt(wo, wo_bf, 2048 * 2048);  // qkv_lat region is free after V^T GEMM
  // ctx = causal_attention(Q, K, V)
  mla_attn<<<512, blk, 0, stream>>>(q_full, k_full, vt, ctx);
  // out = ctx @ Wo^T + bo  (fp32)
  gemm_bt<1><<<dim3(32, 16), blk, 0, stream>>>(ctx, wo_bf, (float*)d_out, bo,
                                               2048, 2048, 2048, 2048, 2048, 1.0f);
}

// Round 3
// 277.708 us; speedup vs baseline: 1.2287x; 1.2006x over previous
//
#include <hip/hip_runtime.h>

typedef __bf16 bf16x8 __attribute__((ext_vector_type(8)));
typedef float f32x4 __attribute__((ext_vector_type(4)));
typedef unsigned short u16x4 __attribute__((ext_vector_type(4)));

#define L2E 1.44269504088896340736f

__device__ __forceinline__ f32x4 mfma16(bf16x8 a, bf16x8 b, f32x4 c) {
  return __builtin_amdgcn_mfma_f32_16x16x32_bf16(a, b, c, 0, 0, 0);
}

// global -> LDS direct copy, 16B per lane. LDS dest must be wave-uniform;
// lane l lands at dest + l*16 bytes.
__device__ __forceinline__ void async16(const __bf16* g, __bf16* l) {
  __builtin_amdgcn_global_load_lds(
      (const __attribute__((address_space(1))) void*)g,
      (__attribute__((address_space(3))) void*)l, 16, 0, 0);
}

// ---------------- fp32 -> bf16 conversion (vectorized) ----------------
__global__ __launch_bounds__(256) void cvt_bf16(const float* __restrict__ s,
                                                __bf16* __restrict__ d) {
  long i = (long)(blockIdx.x * 256 + threadIdx.x) * 4;
  f32x4 v = *(const f32x4*)(s + i);
  u16x4 o;
#pragma unroll
  for (int j = 0; j < 4; j++) o[j] = __builtin_bit_cast(unsigned short, (__bf16)v[j]);
  *(u16x4*)((unsigned short*)d + i) = o;
}

// ---------------- bf16 GEMM: C[M,N] = A[M,K] @ Bt[N,K]^T ----------------
// 128x128 tile, BK=32, 4 waves, 16x16x32 MFMA, global_load_lds staging.
// Strided views supported (lda/ldb/ldc) so fused buffers can be sliced.
// LDS layout swizzled: tile[row][c] stored at LDS[row*32 + (c ^ 8*(row&3))].
template <int OUTF32>
__global__ __launch_bounds__(256, 2) void gemm_bt(
    const __bf16* __restrict__ A, const __bf16* __restrict__ Bt,
    void* __restrict__ Cout, const float* __restrict__ bias,
    int lda, int ldb, int ldc, int N, int K, float scale) {
  __shared__ __align__(16) __bf16 As[4096];
  __shared__ __align__(16) __bf16 Bs[4096];
  const int tid = threadIdx.x;
  const int wid = tid >> 6, lane = tid & 63;
  const int lrow = lane & 15, lkhi = lane >> 4;
  const int row0 = blockIdx.x * 128, col0 = blockIdx.y * 128;
  const int wr = (wid >> 1) * 64, wc = (wid & 1) * 64;

  // staging: thread tid covers LDS elements tid*8..+7 (issue 0) / +2048 (issue 1)
  const int trow = tid >> 2;                       // tile row within issue
  const int scol = 8 * ((tid & 3) ^ (trow & 3));   // pre-swizzled source col
  const __bf16* pA0 = A + (size_t)(row0 + trow) * lda + scol;
  const __bf16* pA1 = pA0 + (size_t)64 * lda;
  const __bf16* pB0 = Bt + (size_t)(col0 + trow) * ldb + scol;
  const __bf16* pB1 = pB0 + (size_t)64 * ldb;
  __bf16* lA0 = As + wid * 512;
  __bf16* lA1 = As + 2048 + wid * 512;
  __bf16* lB0 = Bs + wid * 512;
  __bf16* lB1 = Bs + 2048 + wid * 512;

  int aoff[4], boff[4];
#pragma unroll
  for (int i = 0; i < 4; i++) {
    int rr = wr + i * 16 + lrow;
    aoff[i] = rr * 32 + 8 * (lkhi ^ (rr & 3));
    rr = wc + i * 16 + lrow;
    boff[i] = rr * 32 + 8 * (lkhi ^ (rr & 3));
  }

  f32x4 acc[4][4] = {};
  for (int k0 = 0; k0 < K; k0 += 32) {
    __syncthreads();  // prev compute done before overwriting LDS
    async16(pA0, lA0);
    async16(pA1, lA1);
    async16(pB0, lB0);
    async16(pB1, lB1);
    pA0 += 32; pA1 += 32; pB0 += 32; pB1 += 32;
    __syncthreads();  // staging visible (compiler drains vmcnt before barrier)
    bf16x8 af[4], bv[4];
#pragma unroll
    for (int mi = 0; mi < 4; mi++) af[mi] = *(const bf16x8*)(As + aoff[mi]);
#pragma unroll
    for (int ni = 0; ni < 4; ni++) bv[ni] = *(const bf16x8*)(Bs + boff[ni]);
#pragma unroll
    for (int mi = 0; mi < 4; mi++)
#pragma unroll
      for (int ni = 0; ni < 4; ni++)
        acc[mi][ni] = mfma16(af[mi], bv[ni], acc[mi][ni]);
  }

  const int orow = row0 + wr + lkhi * 4;
  const int ocol = col0 + wc + lrow;
#pragma unroll
  for (int mi = 0; mi < 4; mi++)
#pragma unroll
    for (int ni = 0; ni < 4; ni++)
#pragma unroll
      for (int r = 0; r < 4; r++) {
        size_t idx = (size_t)(orow + mi * 16 + r) * ldc + (ocol + ni * 16);
        float v = acc[mi][ni][r] * scale;
        if (OUTF32)
          ((float*)Cout)[idx] = v + bias[ocol + ni * 16];
        else
          ((__bf16*)Cout)[idx] = (__bf16)v;
      }
}

// ---------------- causal flash attention (balanced pairs, KVBLK=128) -----
// Qf,Kf: [B*T, H*DH] bf16 (Q pre-scaled by 1/sqrt(DH)); Vt: [H*DH, B*T] bf16.
// Grid: 256 = B(2) * H(16) * 8 pair-index j. Block = 128 q-rows (4 waves x
// 32 rows), handles q-tile pair {j, 15-j} -> uniform 17 KV-tiles of 128 keys.
// K double-buffered; V staged early (latency hides under QK^T+softmax).
__global__ __launch_bounds__(256, 1) void mla_attn(
    const __bf16* __restrict__ Qf, const __bf16* __restrict__ Kf,
    const __bf16* __restrict__ Vt, __bf16* __restrict__ ctx) {
  __shared__ __align__(16) __bf16 Ks[2 * 128 * 128];  // dbuf [key][dh], swz &7
  __shared__ __align__(16) __bf16 Vs[128 * 128];      // [dh][key], swz &7
  __shared__ __align__(16) __bf16 Ps[4][32 * 128];    // per-wave P, swz &7

  // XCD swizzle: 256 blocks, 8 XCDs; XCD x gets 32 consecutive ids =
  // 4 whole (b,h) groups -> its K/V working set (4MB) fits one L2.
  const int bid = (int)((blockIdx.x & 7) * 32 + (blockIdx.x >> 3));
  const int j = bid & 7, h = (bid >> 3) & 15, b = bid >> 7;
  const int tid = threadIdx.x, wid = tid >> 6, lane = tid & 63;
  const int lrow = lane & 15, lkhi = lane >> 4;
  __bf16* ps = &Ps[wid][0];

  const __bf16* Kbh = Kf + (size_t)b * 2048 * 2048 + h * 128;
  const __bf16* Vbh = Vt + (size_t)h * 128 * 4096 + b * 2048;

  auto stageK = [&](int k0, __bf16* dst) {
#pragma unroll
    for (int i = 0; i < 8; i++) {
      int oe = i * 2048 + tid * 8;
      int row = oe >> 7;
      int cs = (oe & 127) ^ (8 * (row & 7));
      async16(Kbh + (size_t)(k0 + row) * 2048 + cs, dst + i * 2048 + wid * 512);
    }
  };
  auto stageV = [&](int k0) {
#pragma unroll
    for (int i = 0; i < 8; i++) {
      int oe = i * 2048 + tid * 8;
      int row = oe >> 7;
      int cs = (oe & 127) ^ (8 * (row & 7));
      async16(Vbh + (size_t)row * 4096 + k0 + cs, Vs + i * 2048 + wid * 512);
    }
  };

  for (int seg = 0; seg < 2; seg++) {
    const int qt = seg ? (15 - j) : j;  // 128-row q-tile index
    const int q0 = qt * 128;
    const int nkv = qt + 1;             // KV tiles of 128 keys

    // Q fragments in registers (A-operand layout), read once per segment.
    bf16x8 qa[2][4];
#pragma unroll
    for (int mi = 0; mi < 2; mi++)
#pragma unroll
      for (int kk = 0; kk < 4; kk++)
        qa[mi][kk] = *(const bf16x8*)(Qf +
            (size_t)(b * 2048 + q0 + wid * 32 + mi * 16 + lrow) * 2048 +
            h * 128 + kk * 32 + lkhi * 8);

    f32x4 o_acc[2][8] = {};
    float mrow[2][4], lsum[2][4];
#pragma unroll
    for (int mi = 0; mi < 2; mi++)
#pragma unroll
      for (int r = 0; r < 4; r++) { mrow[mi][r] = -1e30f; lsum[mi][r] = 0.f; }

    int cur = 0;
    stageK(0, Ks);  // safe: post last-E barrier no wave reads Ks

    for (int kb = 0; kb < nkv; kb++) {
      const int k0 = kb * 128;
      __syncthreads();  // A: K[kb] staged; Vs & Ks[cur^1] free for restage
      stageV(k0);
      if (kb + 1 < nkv) stageK(k0 + 128, Ks + (cur ^ 1) * 16384);

      // S = Q K^T (contraction over dh), from Ks[cur]
      const __bf16* kc = Ks + cur * 16384;
      f32x4 s_acc[2][8] = {};
#pragma unroll
      for (int kk = 0; kk < 4; kk++) {
#pragma unroll
        for (int ni = 0; ni < 8; ni++) {
          int row = ni * 16 + lrow;
          bf16x8 kf = *(const bf16x8*)(kc + row * 128 +
                                       ((kk * 32 + lkhi * 8) ^ (8 * (row & 7))));
          s_acc[0][ni] = mfma16(qa[0][kk], kf, s_acc[0][ni]);
          s_acc[1][ni] = mfma16(qa[1][kk], kf, s_acc[1][ni]);
        }
      }

      // causal mask: only the diagonal (last) KV tile crosses it
      if (kb == nkv - 1) {
#pragma unroll
        for (int mi = 0; mi < 2; mi++)
#pragma unroll
          for (int ni = 0; ni < 8; ni++)
#pragma unroll
            for (int r = 0; r < 4; r++) {
              int q = q0 + wid * 32 + mi * 16 + lkhi * 4 + r;
              int kx = k0 + ni * 16 + lrow;
              if (kx > q) s_acc[mi][ni][r] = -1e30f;
            }
      }

      // online softmax with deferred rescale (THR=8)
      float bm[2][4];
#pragma unroll
      for (int mi = 0; mi < 2; mi++)
#pragma unroll
        for (int r = 0; r < 4; r++) {
          float a0 = fmaxf(fmaxf(s_acc[mi][0][r], s_acc[mi][1][r]),
                           fmaxf(s_acc[mi][2][r], s_acc[mi][3][r]));
          float a1 = fmaxf(fmaxf(s_acc[mi][4][r], s_acc[mi][5][r]),
                           fmaxf(s_acc[mi][6][r], s_acc[mi][7][r]));
          float v = fmaxf(a0, a1);
          v = fmaxf(v, __shfl_xor(v, 1));
          v = fmaxf(v, __shfl_xor(v, 2));
          v = fmaxf(v, __shfl_xor(v, 4));
          v = fmaxf(v, __shfl_xor(v, 8));
          bm[mi][r] = v;
        }
      int grow = 0;
#pragma unroll
      for (int mi = 0; mi < 2; mi++)
#pragma unroll
        for (int r = 0; r < 4; r++)
          grow |= (bm[mi][r] > mrow[mi][r] + 8.f);
      if (__any(grow)) {
#pragma unroll
        for (int mi = 0; mi < 2; mi++)
#pragma unroll
          for (int r = 0; r < 4; r++) {
            float mn = fmaxf(mrow[mi][r], bm[mi][r]);
            float sf = __builtin_amdgcn_exp2f((mrow[mi][r] - mn) * L2E);
            mrow[mi][r] = mn;
            lsum[mi][r] *= sf;
#pragma unroll
            for (int n2 = 0; n2 < 8; n2++) o_acc[mi][n2][r] *= sf;
          }
      }
#pragma unroll
      for (int mi = 0; mi < 2; mi++)
#pragma unroll
        for (int r = 0; r < 4; r++) {
          float mr = mrow[mi][r];
          int prow = mi * 16 + lkhi * 4 + r;
          int sw = 8 * (prow & 7);
          float psum = 0.f;
#pragma unroll
          for (int ni = 0; ni < 8; ni++) {
            float p = __builtin_amdgcn_exp2f((s_acc[mi][ni][r] - mr) * L2E);
            psum += p;
            ps[prow * 128 + ((ni * 16 + lrow) ^ sw)] = (__bf16)p;
          }
          psum += __shfl_xor(psum, 1);
          psum += __shfl_xor(psum, 2);
          psum += __shfl_xor(psum, 4);
          psum += __shfl_xor(psum, 8);
          lsum[mi][r] += psum;
        }

      __syncthreads();  // E: V[kb] (and K[kb+1]) drained into LDS

      // O += P V (contraction over 128 keys)
#pragma unroll
      for (int kk = 0; kk < 4; kk++) {
        bf16x8 pa[2];
#pragma unroll
        for (int mi = 0; mi < 2; mi++) {
          int row = mi * 16 + lrow;
          pa[mi] = *(const bf16x8*)(ps + row * 128 +
                                    ((kk * 32 + lkhi * 8) ^ (8 * (row & 7))));
        }
#pragma unroll
        for (int n2 = 0; n2 < 8; n2++) {
          int vrow = n2 * 16 + lrow;
          bf16x8 vf = *(const bf16x8*)(Vs + vrow * 128 +
                                       ((kk * 32 + lkhi * 8) ^ (8 * (vrow & 7))));
          o_acc[0][n2] = mfma16(pa[0], vf, o_acc[0][n2]);
          o_acc[1][n2] = mfma16(pa[1], vf, o_acc[1][n2]);
        }
      }
      cur ^= 1;
    }

    // normalize and write ctx [B*T, H*DH] bf16
#pragma unroll
    for (int mi = 0; mi < 2; mi++)
#pragma unroll
      for (int r = 0; r < 4; r++) {
        float inv = 1.f / lsum[mi][r];
        size_t rowi = (size_t)(b * 2048 + q0 + wid * 32 + mi * 16 + lkhi * 4 + r) * 2048 +
                      h * 128;
#pragma unroll
        for (int n2 = 0; n2 < 8; n2++)
          ctx[rowi + n2 * 16 + lrow] = (__bf16)(o_acc[mi][n2][r] * inv);
      }
  }
}

// ---------------- launch ----------------
extern "C" void kernel_launch(void* const* d_in, const int* in_sizes, int n_in,
                              void* d_out, int out_size, void* d_ws, size_t ws_size,
                              hipStream_t stream) {
  (void)in_sizes; (void)n_in; (void)out_size; (void)ws_size;
  const float* x    = (const float*)d_in[0];
  const float* wqd  = (const float*)d_in[1];
  const float* wkvd = (const float*)d_in[2];
  const float* wqup = (const float*)d_in[3];
  const float* wkup = (const float*)d_in[4];
  const float* wvup = (const float*)d_in[5];
  const float* wo   = (const float*)d_in[6];
  const float* bo   = (const float*)d_in[7];

  char* ws = (char*)d_ws;
  const size_t MB = 1024 * 1024;
  __bf16* x_bf     = (__bf16*)(ws + 0);        // 16MB; reused as ctx
  __bf16* q_full   = (__bf16*)(ws + 16 * MB);  // 16MB
  __bf16* k_full   = (__bf16*)(ws + 32 * MB);  // 16MB
  __bf16* vt       = (__bf16*)(ws + 48 * MB);  // 16MB
  __bf16* qkv_lat  = (__bf16*)(ws + 64 * MB);  // 12MB [4096,1536]; reused wo_bf
  __bf16* wqkvd_bf = (__bf16*)(ws + 76 * MB);  // 6MB  [1536,2048] fused
  __bf16* wqup_bf  = (__bf16*)(ws + 82 * MB);  // 4MB
  __bf16* wkup_bf  = (__bf16*)(ws + 86 * MB);  // 2MB
  __bf16* wvup_bf  = (__bf16*)(ws + 88 * MB);  // 2MB -> total 90MB
  __bf16* ctx   = x_bf;      // x_bf dead after fused down-proj
  __bf16* wo_bf = qkv_lat;   // qkv_lat dead after V^T GEMM

  auto cvt = [&](const float* s, __bf16* d, int n) {
    cvt_bf16<<<n / 1024, 256, 0, stream>>>(s, d);
  };
  cvt(x, x_bf, 4096 * 2048);
  cvt(wqd, wqkvd_bf, 1024 * 2048);                  // rows 0..1023
  cvt(wkvd, wqkvd_bf + 1024 * 2048, 512 * 2048);    // rows 1024..1535
  cvt(wqup, wqup_bf, 2048 * 1024);
  cvt(wkup, wkup_bf, 2048 * 512);
  cvt(wvup, wvup_bf, 2048 * 512);

  dim3 blk(256);
  // [Q_lat | C_kv] = x @ [Wq_down; Wkv_down]^T   (fused, N=1536)
  gemm_bt<0><<<dim3(32, 12), blk, 0, stream>>>(x_bf, wqkvd_bf, qkv_lat, nullptr,
                                               2048, 2048, 1536, 1536, 2048, 1.0f);
  // Q = Q_lat @ Wq_up^T, pre-scaled by 1/sqrt(128)
  gemm_bt<0><<<dim3(32, 16), blk, 0, stream>>>(qkv_lat, wqup_bf, q_full, nullptr,
                                               1536, 1024, 2048, 2048, 1024,
                                               0.08838834764831845f);
  // K = C_kv @ Wk_up^T
  gemm_bt<0><<<dim3(32, 16), blk, 0, stream>>>(qkv_lat + 1024, wkup_bf, k_full,
                                               nullptr, 1536, 512, 2048, 2048,
                                               512, 1.0f);
  // V^T = Wv_up @ C_kv^T  (same kernel, operand roles swapped)
  gemm_bt<0><<<dim3(16, 32), blk, 0, stream>>>(wvup_bf, qkv_lat + 1024, vt,
                                               nullptr, 512, 1536, 4096, 4096,
                                               512, 1.0f);
  cvt(wo, wo_bf, 2048 * 2048);  // qkv_lat region is free after V^T GEMM
  // ctx = causal_attention(Q, K, V)
  mla_attn<<<256, blk, 0, stream>>>(q_full, k_full, vt, ctx);
  // out = ctx @ Wo^T + bo  (fp32)
  gemm_bt<1><<<dim3(32, 16), blk, 0, stream>>>(ctx, wo_bf, (float*)d_out, bo,
                                               2048, 2048, 2048, 2048, 2048, 1.0f);
}

// Round 4
// 248.086 us; speedup vs baseline: 1.3754x; 1.1194x over previous
//
#include <hip/hip_runtime.h>

typedef __bf16 bf16x8 __attribute__((ext_vector_type(8)));
typedef float f32x4 __attribute__((ext_vector_type(4)));
typedef float f32x16 __attribute__((ext_vector_type(16)));
typedef unsigned short u16x4 __attribute__((ext_vector_type(4)));
typedef unsigned int u32x4 __attribute__((ext_vector_type(4)));

#define L2E 1.44269504088896340736f

__device__ __forceinline__ f32x4 mfma16(bf16x8 a, bf16x8 b, f32x4 c) {
  return __builtin_amdgcn_mfma_f32_16x16x32_bf16(a, b, c, 0, 0, 0);
}
__device__ __forceinline__ f32x16 mfma32(bf16x8 a, bf16x8 b, f32x16 c) {
  return __builtin_amdgcn_mfma_f32_32x32x16_bf16(a, b, c, 0, 0, 0);
}

// global -> LDS direct copy, 16B per lane. LDS dest must be wave-uniform;
// lane l lands at dest + l*16 bytes.
__device__ __forceinline__ void async16(const __bf16* g, __bf16* l) {
  __builtin_amdgcn_global_load_lds(
      (const __attribute__((address_space(1))) void*)g,
      (__attribute__((address_space(3))) void*)l, 16, 0, 0);
}

// pack two f32 -> one u32 of 2 bf16 (lo=x, hi=y)
__device__ __forceinline__ unsigned pk(float x, float y) {
  unsigned short lo = __builtin_bit_cast(unsigned short, (__bf16)x);
  unsigned short hi = __builtin_bit_cast(unsigned short, (__bf16)y);
  return ((unsigned)hi << 16) | (unsigned)lo;
}

// exchange halves: a' = [a_lo | b_lo], b' = [a_hi | b_hi]
__device__ __forceinline__ void swap32(unsigned& a, unsigned& b, bool hi) {
  unsigned ax = (unsigned)__shfl_xor((int)a, 32);
  unsigned bx = (unsigned)__shfl_xor((int)b, 32);
  unsigned na = hi ? bx : a;
  unsigned nb = hi ? b : ax;
  a = na; b = nb;
}

// ---------------- fp32 -> bf16 conversion (vectorized) ----------------
__global__ __launch_bounds__(256) void cvt_bf16(const float* __restrict__ s,
                                                __bf16* __restrict__ d) {
  long i = (long)(blockIdx.x * 256 + threadIdx.x) * 4;
  f32x4 v = *(const f32x4*)(s + i);
  u16x4 o;
#pragma unroll
  for (int j = 0; j < 4; j++) o[j] = __builtin_bit_cast(unsigned short, (__bf16)v[j]);
  *(u16x4*)((unsigned short*)d + i) = o;
}

// ---------------- bf16 GEMM: C[M,N] = A[M,K] @ Bt[N,K]^T ----------------
// 128x128 tile, BK=32, 4 waves, 16x16x32 MFMA, global_load_lds staging.
// Strided views supported (lda/ldb/ldc) so fused buffers can be sliced.
// LDS layout swizzled: tile[row][c] stored at LDS[row*32 + (c ^ 8*(row&3))].
template <int OUTF32>
__global__ __launch_bounds__(256, 2) void gemm_bt(
    const __bf16* __restrict__ A, const __bf16* __restrict__ Bt,
    void* __restrict__ Cout, const float* __restrict__ bias,
    int lda, int ldb, int ldc, int N, int K, float scale) {
  __shared__ __align__(16) __bf16 As[4096];
  __shared__ __align__(16) __bf16 Bs[4096];
  const int tid = threadIdx.x;
  const int wid = tid >> 6, lane = tid & 63;
  const int lrow = lane & 15, lkhi = lane >> 4;
  const int row0 = blockIdx.x * 128, col0 = blockIdx.y * 128;
  const int wr = (wid >> 1) * 64, wc = (wid & 1) * 64;

  const int trow = tid >> 2;                       // tile row within issue
  const int scol = 8 * ((tid & 3) ^ (trow & 3));   // pre-swizzled source col
  const __bf16* pA0 = A + (size_t)(row0 + trow) * lda + scol;
  const __bf16* pA1 = pA0 + (size_t)64 * lda;
  const __bf16* pB0 = Bt + (size_t)(col0 + trow) * ldb + scol;
  const __bf16* pB1 = pB0 + (size_t)64 * ldb;
  __bf16* lA0 = As + wid * 512;
  __bf16* lA1 = As + 2048 + wid * 512;
  __bf16* lB0 = Bs + wid * 512;
  __bf16* lB1 = Bs + 2048 + wid * 512;

  int aoff[4], boff[4];
#pragma unroll
  for (int i = 0; i < 4; i++) {
    int rr = wr + i * 16 + lrow;
    aoff[i] = rr * 32 + 8 * (lkhi ^ (rr & 3));
    rr = wc + i * 16 + lrow;
    boff[i] = rr * 32 + 8 * (lkhi ^ (rr & 3));
  }

  f32x4 acc[4][4] = {};
  for (int k0 = 0; k0 < K; k0 += 32) {
    __syncthreads();
    async16(pA0, lA0);
    async16(pA1, lA1);
    async16(pB0, lB0);
    async16(pB1, lB1);
    pA0 += 32; pA1 += 32; pB0 += 32; pB1 += 32;
    __syncthreads();
    bf16x8 af[4], bv[4];
#pragma unroll
    for (int mi = 0; mi < 4; mi++) af[mi] = *(const bf16x8*)(As + aoff[mi]);
#pragma unroll
    for (int ni = 0; ni < 4; ni++) bv[ni] = *(const bf16x8*)(Bs + boff[ni]);
#pragma unroll
    for (int mi = 0; mi < 4; mi++)
#pragma unroll
      for (int ni = 0; ni < 4; ni++)
        acc[mi][ni] = mfma16(af[mi], bv[ni], acc[mi][ni]);
  }

  const int orow = row0 + wr + lkhi * 4;
  const int ocol = col0 + wc + lrow;
#pragma unroll
  for (int mi = 0; mi < 4; mi++)
#pragma unroll
    for (int ni = 0; ni < 4; ni++)
#pragma unroll
      for (int r = 0; r < 4; r++) {
        size_t idx = (size_t)(orow + mi * 16 + r) * ldc + (ocol + ni * 16);
        float v = acc[mi][ni][r] * scale;
        if (OUTF32)
          ((float*)Cout)[idx] = v + bias[ocol + ni * 16];
        else
          ((__bf16*)Cout)[idx] = (__bf16)v;
      }
}

// ---------------- causal flash attention (swapped QK^T, in-reg softmax) --
// Qf,Kf: [B*T, H*DH] bf16 (Q pre-scaled by L2E/sqrt(DH)); Vt: [H*DH,B*T].
// Grid: 256 = B(2)*H(16)*8 pair-index j; block = 4 waves x 32 q-rows =
// 128 q-rows, handles q-tile pair {j, 15-j} -> uniform 34 KV-tiles of 64.
// S^T = mfma32(K, Q): lane holds 32 P-values for ONE q-row (q = lane&31,
// dup across halves) -> softmax fully in-register; P repacks to the PV
// A-operand with 16 packs + 8 half-swaps. K,V double-buffered in LDS,
// ONE barrier per tile.
__global__ __launch_bounds__(256, 1) void mla_attn(
    const __bf16* __restrict__ Qf, const __bf16* __restrict__ Kf,
    const __bf16* __restrict__ Vt, __bf16* __restrict__ ctx) {
  __shared__ __align__(16) __bf16 Ks[2][64 * 128];  // [key][dh], swz (row&15)
  __shared__ __align__(16) __bf16 Vs[2][128 * 64];  // [dh][key], swz (row&7)

  // XCD swizzle: 256 blocks, 8 XCDs; XCD x gets 32 consecutive ids =
  // 4 whole (b,h) groups -> K/V working set fits one L2.
  const int bid = (int)((blockIdx.x & 7) * 32 + (blockIdx.x >> 3));
  const int j = bid & 7, h = (bid >> 3) & 15, b = bid >> 7;
  const int tid = threadIdx.x, wid = tid >> 6, lane = tid & 63;
  const int l31 = lane & 31;
  const bool hh = (lane & 32) != 0;  // half index

  const __bf16* Kbh = Kf + (size_t)b * 2048 * 2048 + h * 128;
  const __bf16* Vbh = Vt + (size_t)h * 128 * 4096 + b * 2048;

  auto stage = [&](int k0, int buf) {
#pragma unroll
    for (int i = 0; i < 4; i++) {
      int e = i * 2048 + tid * 8;
      int krow = e >> 7;
      int kcol = (e & 127) ^ (8 * (krow & 15));
      async16(Kbh + (size_t)(k0 + krow) * 2048 + kcol,
              &Ks[buf][i * 2048 + wid * 512]);
    }
#pragma unroll
    for (int i = 0; i < 4; i++) {
      int e = i * 2048 + tid * 8;
      int vrow = e >> 6;
      int vcol = (e & 63) ^ (8 * (vrow & 7));
      async16(Vbh + (size_t)vrow * 4096 + k0 + vcol,
              &Vs[buf][i * 2048 + wid * 512]);
    }
  };

  int cur = 0;
  for (int seg = 0; seg < 2; seg++) {
    const int qt = seg ? (15 - j) : j;  // 128-row q-tile index
    const int q0 = qt * 128;
    const int nkv = 2 * qt + 2;         // 64-key tiles
    const int q = q0 + wid * 32 + l31;  // this lane's q-row

    // Q fragments (B-operand layout: col=q=lane&31, k-rows (lane>>5)*8+j)
    bf16x8 qb[8];
    const __bf16* qrow =
        Qf + (size_t)(b * 2048 + q) * 2048 + h * 128 + (hh ? 8 : 0);
#pragma unroll
    for (int ds = 0; ds < 8; ds++) qb[ds] = *(const bf16x8*)(qrow + ds * 16);

    f32x16 o[4] = {};
    float mrow = -1e30f, lsum = 0.f;

    __syncthreads();  // prior segment's LDS reads complete
    stage(0, cur);

    for (int kb = 0; kb < nkv; kb++) {
      const int k0 = kb * 64;
      __syncthreads();  // buf[cur] staged; buf[cur^1] free
      if (kb + 1 < nkv) stage(k0 + 64, cur ^ 1);

      // S^T = K Q^T : sacc[kt][r] = S[key = k0+kt*32+(r&3)+8*(r>>2)+4*hh][q]
      f32x16 sacc[2] = {};
#pragma unroll
      for (int ds = 0; ds < 8; ds++) {
#pragma unroll
        for (int kt = 0; kt < 2; kt++) {
          int row = kt * 32 + l31;
          int col = (ds * 16 + (hh ? 8 : 0)) ^ (8 * (row & 15));
          bf16x8 kf = *(const bf16x8*)(&Ks[cur][row * 128 + col]);
          sacc[kt] = mfma32(kf, qb[ds], sacc[kt]);
        }
      }

      // causal mask (last two tiles only)
      if (kb >= 2 * qt) {
#pragma unroll
        for (int kt = 0; kt < 2; kt++)
#pragma unroll
          for (int r = 0; r < 16; r++) {
            int key = k0 + kt * 32 + (r & 3) + 8 * (r >> 2) + (hh ? 4 : 0);
            if (key > q) sacc[kt][r] = -1e30f;
          }
      }

      // in-register online softmax (s already in log2 units)
      float pm = sacc[0][0];
#pragma unroll
      for (int r = 1; r < 16; r++) pm = fmaxf(pm, sacc[0][r]);
#pragma unroll
      for (int r = 0; r < 16; r++) pm = fmaxf(pm, sacc[1][r]);
      pm = fmaxf(pm, __shfl_xor(pm, 32));
      if (__any(pm > mrow + 8.f)) {  // deferred rescale (THR=8 log2)
        float mn = fmaxf(mrow, pm);
        float sf = __builtin_amdgcn_exp2f(mrow - mn);
        mrow = mn;
        lsum *= sf;
#pragma unroll
        for (int r = 0; r < 16; r++) {
          int ql = (r & 3) + 8 * (r >> 2) + (hh ? 4 : 0);
          float sr = __shfl(sf, ql);
#pragma unroll
          for (int dt = 0; dt < 4; dt++) o[dt][r] *= sr;
        }
      }
      float ps = 0.f;
#pragma unroll
      for (int kt = 0; kt < 2; kt++)
#pragma unroll
        for (int r = 0; r < 16; r++) {
          float p = __builtin_amdgcn_exp2f(sacc[kt][r] - mrow);
          sacc[kt][r] = p;
          ps += p;
        }
      ps += __shfl_xor(ps, 32);
      lsum += ps;

      // O += P V : repack P (lane-local) into A-operand fragments
#pragma unroll
      for (int s = 0; s < 4; s++) {
        const int kt = s >> 1, r8 = (s & 1) * 8;
        unsigned w0 = pk(sacc[kt][r8 + 0], sacc[kt][r8 + 1]);
        unsigned w2 = pk(sacc[kt][r8 + 4], sacc[kt][r8 + 5]);
        unsigned w1 = pk(sacc[kt][r8 + 2], sacc[kt][r8 + 3]);
        unsigned w3 = pk(sacc[kt][r8 + 6], sacc[kt][r8 + 7]);
        swap32(w0, w2, hh);  // -> keys 16s+{0,1}|{8,9} , {4,5}|{12,13}
        swap32(w1, w3, hh);
        u32x4 wv;
        wv.x = w0; wv.y = w1; wv.z = w2; wv.w = w3;
        bf16x8 pa = __builtin_bit_cast(bf16x8, wv);
#pragma unroll
        for (int dt = 0; dt < 4; dt++) {
          int vrow = dt * 32 + l31;
          int vcol = (s * 16 + (hh ? 8 : 0)) ^ (8 * (vrow & 7));
          bf16x8 vf = *(const bf16x8*)(&Vs[cur][vrow * 64 + vcol]);
          o[dt] = mfma32(pa, vf, o[dt]);
        }
      }
      cur ^= 1;
    }

    // epilogue: normalize, gather per-row inv, write ctx
    float inv = 1.f / lsum;
#pragma unroll
    for (int r = 0; r < 16; r++) {
      int ql = (r & 3) + 8 * (r >> 2) + (hh ? 4 : 0);
      float ir = __shfl(inv, ql);
      size_t rowi =
          (size_t)(b * 2048 + q0 + wid * 32 + ql) * 2048 + h * 128;
#pragma unroll
      for (int dt = 0; dt < 4; dt++)
        ctx[rowi + dt * 32 + l31] = (__bf16)(o[dt][r] * ir);
    }
  }
}

// ---------------- launch ----------------
extern "C" void kernel_launch(void* const* d_in, const int* in_sizes, int n_in,
                              void* d_out, int out_size, void* d_ws, size_t ws_size,
                              hipStream_t stream) {
  (void)in_sizes; (void)n_in; (void)out_size; (void)ws_size;
  const float* x    = (const float*)d_in[0];
  const float* wqd  = (const float*)d_in[1];
  const float* wkvd = (const float*)d_in[2];
  const float* wqup = (const float*)d_in[3];
  const float* wkup = (const float*)d_in[4];
  const float* wvup = (const float*)d_in[5];
  const float* wo   = (const float*)d_in[6];
  const float* bo   = (const float*)d_in[7];

  char* ws = (char*)d_ws;
  const size_t MB = 1024 * 1024;
  __bf16* x_bf     = (__bf16*)(ws + 0);        // 16MB; reused as ctx
  __bf16* q_full   = (__bf16*)(ws + 16 * MB);  // 16MB
  __bf16* k_full   = (__bf16*)(ws + 32 * MB);  // 16MB
  __bf16* vt       = (__bf16*)(ws + 48 * MB);  // 16MB
  __bf16* qkv_lat  = (__bf16*)(ws + 64 * MB);  // 12MB [4096,1536]; reused wo_bf
  __bf16* wqkvd_bf = (__bf16*)(ws + 76 * MB);  // 6MB  [1536,2048] fused
  __bf16* wqup_bf  = (__bf16*)(ws + 82 * MB);  // 4MB
  __bf16* wkup_bf  = (__bf16*)(ws + 86 * MB);  // 2MB
  __bf16* wvup_bf  = (__bf16*)(ws + 88 * MB);  // 2MB -> total 90MB
  __bf16* ctx   = x_bf;      // x_bf dead after fused down-proj
  __bf16* wo_bf = qkv_lat;   // qkv_lat dead after V^T GEMM

  auto cvt = [&](const float* s, __bf16* d, int n) {
    cvt_bf16<<<n / 1024, 256, 0, stream>>>(s, d);
  };
  cvt(x, x_bf, 4096 * 2048);
  cvt(wqd, wqkvd_bf, 1024 * 2048);                  // rows 0..1023
  cvt(wkvd, wqkvd_bf + 1024 * 2048, 512 * 2048);    // rows 1024..1535
  cvt(wqup, wqup_bf, 2048 * 1024);
  cvt(wkup, wkup_bf, 2048 * 512);
  cvt(wvup, wvup_bf, 2048 * 512);

  dim3 blk(256);
  // [Q_lat | C_kv] = x @ [Wq_down; Wkv_down]^T   (fused, N=1536)
  gemm_bt<0><<<dim3(32, 12), blk, 0, stream>>>(x_bf, wqkvd_bf, qkv_lat, nullptr,
                                               2048, 2048, 1536, 1536, 2048, 1.0f);
  // Q = Q_lat @ Wq_up^T, pre-scaled by L2E/sqrt(128) (softmax uses exp2)
  gemm_bt<0><<<dim3(32, 16), blk, 0, stream>>>(qkv_lat, wqup_bf, q_full, nullptr,
                                               1536, 1024, 2048, 2048, 1024,
                                               0.12752039360437355f);
  // K = C_kv @ Wk_up^T
  gemm_bt<0><<<dim3(32, 16), blk, 0, stream>>>(qkv_lat + 1024, wkup_bf, k_full,
                                               nullptr, 1536, 512, 2048, 2048,
                                               512, 1.0f);
  // V^T = Wv_up @ C_kv^T  (same kernel, operand roles swapped)
  gemm_bt<0><<<dim3(16, 32), blk, 0, stream>>>(wvup_bf, qkv_lat + 1024, vt,
                                               nullptr, 512, 1536, 4096, 4096,
                                               512, 1.0f);
  cvt(wo, wo_bf, 2048 * 2048);  // qkv_lat region is free after V^T GEMM
  // ctx = causal_attention(Q, K, V)
  mla_attn<<<256, blk, 0, stream>>>(q_full, k_full, vt, ctx);
  // out = ctx @ Wo^T + bo  (fp32)
  gemm_bt<1><<<dim3(32, 16), blk, 0, stream>>>(ctx, wo_bf, (float*)d_out, bo,
                                               2048, 2048, 2048, 2048, 2048, 1.0f);
}